// Round 1
// baseline (2445.975 us; speedup 1.0000x reference)
//
#include <hip/hip_runtime.h>
#include <math.h>

#define BB 4
#define SQL 2048
#define SKL 2048
#define DM 1024
#define NH 16
#define HDIM 64
#define FSCALE 0.125f

__global__ __launch_bounds__(256)
void zero_f32(float* __restrict__ p, int n) {
    int i = blockIdx.x * 256 + threadIdx.x;
    if (i < n) p[i] = 0.0f;
}

// Wo_eff[n][d] = sum_h Wo[n][h*64+d]
__global__ __launch_bounds__(256)
void wo_eff_kernel(const float* __restrict__ Wo, float* __restrict__ We) {
    int i = blockIdx.x * 256 + threadIdx.x;
    if (i < DM * HDIM) {
        int n = i >> 6, d = i & 63;
        float s = 0.f;
#pragma unroll
        for (int h = 0; h < NH; ++h) s += Wo[(size_t)n * DM + h * HDIM + d];
        We[i] = s;
    }
}

// Y = X @ W^T + bias ; X: MxK row-major, W: NxK row-major (torch Linear)
__global__ __launch_bounds__(256)
void proj_gemm(const float* __restrict__ X, const float* __restrict__ W,
               const float* __restrict__ bias, float* __restrict__ Y,
               int M, int N, int K)
{
    __shared__ float Xs[16][68];  // [k][m]
    __shared__ float Ws[16][68];  // [k][n]
    const int m0 = blockIdx.x * 64, n0 = blockIdx.y * 64;
    const int tid = threadIdx.x;
    const int tx = tid & 15, ty = tid >> 4;
    const int lr = tid >> 2, lc = (tid & 3) << 2;
    float acc[4][4] = {};
    for (int k0 = 0; k0 < K; k0 += 16) {
        float4 xv = *reinterpret_cast<const float4*>(&X[(size_t)(m0 + lr) * K + k0 + lc]);
        float4 wv = *reinterpret_cast<const float4*>(&W[(size_t)(n0 + lr) * K + k0 + lc]);
        __syncthreads();
        Xs[lc + 0][lr] = xv.x; Xs[lc + 1][lr] = xv.y; Xs[lc + 2][lr] = xv.z; Xs[lc + 3][lr] = xv.w;
        Ws[lc + 0][lr] = wv.x; Ws[lc + 1][lr] = wv.y; Ws[lc + 2][lr] = wv.z; Ws[lc + 3][lr] = wv.w;
        __syncthreads();
#pragma unroll
        for (int kk = 0; kk < 16; ++kk) {
            float4 av = *reinterpret_cast<const float4*>(&Xs[kk][ty << 2]);
            float4 bv = *reinterpret_cast<const float4*>(&Ws[kk][tx << 2]);
            float aa[4] = {av.x, av.y, av.z, av.w};
            float bb[4] = {bv.x, bv.y, bv.z, bv.w};
#pragma unroll
            for (int i = 0; i < 4; ++i)
#pragma unroll
                for (int j = 0; j < 4; ++j)
                    acc[i][j] = fmaf(aa[i], bb[j], acc[i][j]);
        }
    }
    float4 bv = *reinterpret_cast<const float4*>(&bias[n0 + (tx << 2)]);
    float bb4[4] = {bv.x, bv.y, bv.z, bv.w};
#pragma unroll
    for (int i = 0; i < 4; ++i) {
        int m = m0 + (ty << 2) + i;
        float4 o = make_float4(acc[i][0] + bb4[0], acc[i][1] + bb4[1],
                               acc[i][2] + bb4[2], acc[i][3] + bb4[3]);
        *reinterpret_cast<float4*>(&Y[(size_t)m * N + n0 + (tx << 2)]) = o;
    }
}

// Flash pass: per (b,h,qtile64): online softmax over k, attended accumulation,
// writes row max m / row sum l, atomically accumulates attended mean (/H, /l).
__global__ __launch_bounds__(256)
void flash_fwd(const float* __restrict__ Qp, const float* __restrict__ Kp,
               const float* __restrict__ Vp, float* __restrict__ mw,
               float* __restrict__ lw, float* __restrict__ am)
{
    __shared__ float Qs[64][68];   // [d][r], pre-scaled by FSCALE
    __shared__ float KPs[64][68];  // K phase: [d][c]; P phase: [c][r]
    __shared__ float Vs[64][68];   // [c][d]
    const int qt = blockIdx.x, h = blockIdx.y, b = blockIdx.z;
    const int q0 = qt << 6;
    const int tid = threadIdx.x;
    const int tx = tid & 15, ty = tid >> 4;
    const int lrow = tid >> 4, ldc = (tid & 15) << 2;

#pragma unroll
    for (int rr = 0; rr < 4; ++rr) {
        int r = (rr << 4) + lrow;
        float4 v = *reinterpret_cast<const float4*>(
            &Qp[(size_t)(b * SQL + q0 + r) * DM + h * HDIM + ldc]);
        Qs[ldc + 0][r] = v.x * FSCALE;
        Qs[ldc + 1][r] = v.y * FSCALE;
        Qs[ldc + 2][r] = v.z * FSCALE;
        Qs[ldc + 3][r] = v.w * FSCALE;
    }
    float m_run[4], l_run[4], att[4][4];
#pragma unroll
    for (int i = 0; i < 4; ++i) {
        m_run[i] = -INFINITY; l_run[i] = 0.f;
#pragma unroll
        for (int j = 0; j < 4; ++j) att[i][j] = 0.f;
    }

    for (int kt = 0; kt < SKL / 64; ++kt) {
        const int k0 = kt << 6;
        float4 kv[4], vv[4];
#pragma unroll
        for (int rr = 0; rr < 4; ++rr) {
            int r = (rr << 4) + lrow;
            kv[rr] = *reinterpret_cast<const float4*>(
                &Kp[(size_t)(b * SKL + k0 + r) * DM + h * HDIM + ldc]);
            vv[rr] = *reinterpret_cast<const float4*>(
                &Vp[(size_t)(b * SKL + k0 + r) * DM + h * HDIM + ldc]);
        }
        __syncthreads();  // prev iter PV reads done
#pragma unroll
        for (int rr = 0; rr < 4; ++rr) {
            int r = (rr << 4) + lrow;
            KPs[ldc + 0][r] = kv[rr].x; KPs[ldc + 1][r] = kv[rr].y;
            KPs[ldc + 2][r] = kv[rr].z; KPs[ldc + 3][r] = kv[rr].w;
            *reinterpret_cast<float4*>(&Vs[r][ldc]) = vv[rr];
        }
        __syncthreads();
        // S = (Q*scale) @ K^T for 64x64 tile
        float s[4][4] = {};
        for (int d = 0; d < 64; ++d) {
            float4 av = *reinterpret_cast<const float4*>(&Qs[d][ty << 2]);
            float4 bv = *reinterpret_cast<const float4*>(&KPs[d][tx << 2]);
            float aa[4] = {av.x, av.y, av.z, av.w};
            float bb[4] = {bv.x, bv.y, bv.z, bv.w};
#pragma unroll
            for (int i = 0; i < 4; ++i)
#pragma unroll
                for (int j = 0; j < 4; ++j)
                    s[i][j] = fmaf(aa[i], bb[j], s[i][j]);
        }
        __syncthreads();  // all K reads done; KPs reusable for P
        float f[4];
#pragma unroll
        for (int i = 0; i < 4; ++i) {
            float rm = fmaxf(fmaxf(s[i][0], s[i][1]), fmaxf(s[i][2], s[i][3]));
            rm = fmaxf(rm, __shfl_xor(rm, 1));
            rm = fmaxf(rm, __shfl_xor(rm, 2));
            rm = fmaxf(rm, __shfl_xor(rm, 4));
            rm = fmaxf(rm, __shfl_xor(rm, 8));
            float mnew = fmaxf(m_run[i], rm);
            f[i] = expf(m_run[i] - mnew);
            float ps = 0.f;
#pragma unroll
            for (int j = 0; j < 4; ++j) {
                float p = expf(s[i][j] - mnew);
                s[i][j] = p; ps += p;
            }
            ps += __shfl_xor(ps, 1);
            ps += __shfl_xor(ps, 2);
            ps += __shfl_xor(ps, 4);
            ps += __shfl_xor(ps, 8);
            l_run[i] = l_run[i] * f[i] + ps;
            m_run[i] = mnew;
#pragma unroll
            for (int j = 0; j < 4; ++j) {
                att[i][j] *= f[i];
                KPs[(tx << 2) + j][(ty << 2) + i] = s[i][j];  // P^T
            }
        }
        __syncthreads();
        // attended += P @ V
        for (int c = 0; c < 64; ++c) {
            float4 av = *reinterpret_cast<const float4*>(&KPs[c][ty << 2]);
            float4 bv = *reinterpret_cast<const float4*>(&Vs[c][tx << 2]);
            float aa[4] = {av.x, av.y, av.z, av.w};
            float bb[4] = {bv.x, bv.y, bv.z, bv.w};
#pragma unroll
            for (int i = 0; i < 4; ++i)
#pragma unroll
                for (int j = 0; j < 4; ++j)
                    att[i][j] = fmaf(aa[i], bb[j], att[i][j]);
        }
    }

#pragma unroll
    for (int i = 0; i < 4; ++i) {
        const int r = q0 + (ty << 2) + i;
        const float inv = 1.0f / l_run[i];
        if (tx == 0) {
            mw[(size_t)(b * NH + h) * SQL + r] = m_run[i];
            lw[(size_t)(b * NH + h) * SQL + r] = l_run[i];
        }
#pragma unroll
        for (int j = 0; j < 4; ++j)
            atomicAdd(&am[(size_t)(b * SQL + r) * HDIM + (tx << 2) + j],
                      att[i][j] * inv * (1.0f / NH));
    }
}

// Second pass: recompute scores per head, emit avg attention tile.
__global__ __launch_bounds__(256)
void avg_attn_kernel(const float* __restrict__ Qp, const float* __restrict__ Kp,
                     const float* __restrict__ mw, const float* __restrict__ lw,
                     float* __restrict__ avg)
{
    __shared__ float Qs[64][68];
    __shared__ float Ks[64][68];
    __shared__ float mS[NH][64];
    __shared__ float ilS[NH][64];
    const int kt = blockIdx.x, qt = blockIdx.y, b = blockIdx.z;
    const int q0 = qt << 6, k0 = kt << 6;
    const int tid = threadIdx.x;
    const int tx = tid & 15, ty = tid >> 4;
    const int lrow = tid >> 4, ldc = (tid & 15) << 2;

    for (int i = tid; i < NH * 64; i += 256) {
        int hh = i >> 6, r = i & 63;
        mS[hh][r] = mw[(size_t)(b * NH + hh) * SQL + q0 + r];
        ilS[hh][r] = 1.0f / (lw[(size_t)(b * NH + hh) * SQL + q0 + r] * (float)NH);
    }

    float acc[4][4] = {};
    for (int h = 0; h < NH; ++h) {
        float4 qv[4], kv[4];
#pragma unroll
        for (int rr = 0; rr < 4; ++rr) {
            int r = (rr << 4) + lrow;
            qv[rr] = *reinterpret_cast<const float4*>(
                &Qp[(size_t)(b * SQL + q0 + r) * DM + h * HDIM + ldc]);
            kv[rr] = *reinterpret_cast<const float4*>(
                &Kp[(size_t)(b * SKL + k0 + r) * DM + h * HDIM + ldc]);
        }
        __syncthreads();  // prev h reads done (also covers mS preload, h=0)
#pragma unroll
        for (int rr = 0; rr < 4; ++rr) {
            int r = (rr << 4) + lrow;
            Qs[ldc + 0][r] = qv[rr].x * FSCALE; Qs[ldc + 1][r] = qv[rr].y * FSCALE;
            Qs[ldc + 2][r] = qv[rr].z * FSCALE; Qs[ldc + 3][r] = qv[rr].w * FSCALE;
            Ks[ldc + 0][r] = kv[rr].x; Ks[ldc + 1][r] = kv[rr].y;
            Ks[ldc + 2][r] = kv[rr].z; Ks[ldc + 3][r] = kv[rr].w;
        }
        __syncthreads();
        float s[4][4] = {};
        for (int d = 0; d < 64; ++d) {
            float4 av = *reinterpret_cast<const float4*>(&Qs[d][ty << 2]);
            float4 bv = *reinterpret_cast<const float4*>(&Ks[d][tx << 2]);
            float aa[4] = {av.x, av.y, av.z, av.w};
            float bb[4] = {bv.x, bv.y, bv.z, bv.w};
#pragma unroll
            for (int i = 0; i < 4; ++i)
#pragma unroll
                for (int j = 0; j < 4; ++j)
                    s[i][j] = fmaf(aa[i], bb[j], s[i][j]);
        }
#pragma unroll
        for (int i = 0; i < 4; ++i) {
            float mv = mS[h][(ty << 2) + i];
            float il = ilS[h][(ty << 2) + i];
#pragma unroll
            for (int j = 0; j < 4; ++j)
                acc[i][j] += expf(s[i][j] - mv) * il;
        }
    }
#pragma unroll
    for (int i = 0; i < 4; ++i) {
        int r = q0 + (ty << 2) + i;
        float4 o = make_float4(acc[i][0], acc[i][1], acc[i][2], acc[i][3]);
        *reinterpret_cast<float4*>(&avg[(size_t)(b * SQL + r) * SKL + k0 + (tx << 2)]) = o;
    }
}

// out = attended_mean @ Wo_eff^T + bo  (M=8192, N=1024, K=64)
__global__ __launch_bounds__(256)
void out_gemm(const float* __restrict__ amp, const float* __restrict__ We,
              const float* __restrict__ bo, float* __restrict__ out)
{
    __shared__ float As[64][68];  // [d][m]
    __shared__ float Bs[64][68];  // [d][n]
    const int m0 = blockIdx.x << 6, n0 = blockIdx.y << 6;
    const int tid = threadIdx.x;
    const int tx = tid & 15, ty = tid >> 4;
    const int lrow = tid >> 4, ldc = (tid & 15) << 2;
#pragma unroll
    for (int rr = 0; rr < 4; ++rr) {
        int r = (rr << 4) + lrow;
        float4 a = *reinterpret_cast<const float4*>(&amp[(size_t)(m0 + r) * HDIM + ldc]);
        float4 w = *reinterpret_cast<const float4*>(&We[(size_t)(n0 + r) * HDIM + ldc]);
        As[ldc + 0][r] = a.x; As[ldc + 1][r] = a.y; As[ldc + 2][r] = a.z; As[ldc + 3][r] = a.w;
        Bs[ldc + 0][r] = w.x; Bs[ldc + 1][r] = w.y; Bs[ldc + 2][r] = w.z; Bs[ldc + 3][r] = w.w;
    }
    __syncthreads();
    float acc[4][4] = {};
    for (int d = 0; d < 64; ++d) {
        float4 av = *reinterpret_cast<const float4*>(&As[d][ty << 2]);
        float4 bv = *reinterpret_cast<const float4*>(&Bs[d][tx << 2]);
        float aa[4] = {av.x, av.y, av.z, av.w};
        float bb[4] = {bv.x, bv.y, bv.z, bv.w};
#pragma unroll
        for (int i = 0; i < 4; ++i)
#pragma unroll
            for (int j = 0; j < 4; ++j)
                acc[i][j] = fmaf(aa[i], bb[j], acc[i][j]);
    }
    float4 bv = *reinterpret_cast<const float4*>(&bo[n0 + (tx << 2)]);
    float bb4[4] = {bv.x, bv.y, bv.z, bv.w};
#pragma unroll
    for (int i = 0; i < 4; ++i) {
        int m = m0 + (ty << 2) + i;
        float4 o = make_float4(acc[i][0] + bb4[0], acc[i][1] + bb4[1],
                               acc[i][2] + bb4[2], acc[i][3] + bb4[3]);
        *reinterpret_cast<float4*>(&out[(size_t)m * DM + n0 + (tx << 2)]) = o;
    }
}

extern "C" void kernel_launch(void* const* d_in, const int* in_sizes, int n_in,
                              void* d_out, int out_size, void* d_ws, size_t ws_size,
                              hipStream_t stream)
{
    const float* query = (const float*)d_in[0];
    const float* key   = (const float*)d_in[1];
    const float* value = (const float*)d_in[2];
    const float* Wq = (const float*)d_in[3];
    const float* bq = (const float*)d_in[4];
    const float* Wk = (const float*)d_in[5];
    const float* bk = (const float*)d_in[6];
    const float* Wv = (const float*)d_in[7];
    const float* bv = (const float*)d_in[8];
    const float* Wo = (const float*)d_in[9];
    const float* bo = (const float*)d_in[10];

    float* out0 = (float*)d_out;                         // (B,SQ,D)
    float* out_avg = out0 + (size_t)BB * SQL * DM;       // (B,SQ,SK)

    float* ws = (float*)d_ws;
    const size_t nQ  = (size_t)BB * SQL * DM;   // 8388608
    const size_t nML = (size_t)BB * NH * SQL;   // 131072
    const size_t nAM = (size_t)BB * SQL * HDIM; // 524288
    float* Qb  = ws;
    float* Kb  = Qb + nQ;
    float* Vb  = Kb + nQ;
    float* mw  = Vb + nQ;
    float* lw  = mw + nML;
    float* amb = lw + nML;
    float* We  = amb + nAM;

    dim3 blk(256);
    zero_f32<<<dim3((unsigned)((nAM + 255) / 256)), blk, 0, stream>>>(amb, (int)nAM);
    wo_eff_kernel<<<dim3((DM * HDIM + 255) / 256), blk, 0, stream>>>(Wo, We);

    dim3 gp(8192 / 64, DM / 64);
    proj_gemm<<<gp, blk, 0, stream>>>(query, Wq, bq, Qb, 8192, DM, DM);
    proj_gemm<<<gp, blk, 0, stream>>>(key,   Wk, bk, Kb, 8192, DM, DM);
    proj_gemm<<<gp, blk, 0, stream>>>(value, Wv, bv, Vb, 8192, DM, DM);

    flash_fwd<<<dim3(SQL / 64, NH, BB), blk, 0, stream>>>(Qb, Kb, Vb, mw, lw, amb);
    avg_attn_kernel<<<dim3(SKL / 64, SQL / 64, BB), blk, 0, stream>>>(Qb, Kb, mw, lw, out_avg);
    out_gemm<<<dim3(8192 / 64, DM / 64), blk, 0, stream>>>(amb, We, bo, out0);
}

// Round 2
// 462.290 us; speedup vs baseline: 5.2910x; 5.2910x over previous
//
#include <hip/hip_runtime.h>
#include <hip/hip_bf16.h>
#include <math.h>

#define BB 4
#define SQL 2048
#define SKL 2048
#define DM 1024
#define NH 16
#define HDIM 64
#define FSCALE 0.125f

typedef __attribute__((ext_vector_type(8))) short bf16x8;
typedef __attribute__((ext_vector_type(4))) float f32x4;

__device__ __forceinline__ unsigned short f2bf(float f) {
    union { __hip_bfloat16 h; unsigned short u; } c;
    c.h = __float2bfloat16(f);
    return c.u;
}

__device__ __forceinline__ bf16x8 cvt8(const float4& a, const float4& b) {
    bf16x8 r;
    r[0] = (short)f2bf(a.x); r[1] = (short)f2bf(a.y);
    r[2] = (short)f2bf(a.z); r[3] = (short)f2bf(a.w);
    r[4] = (short)f2bf(b.x); r[5] = (short)f2bf(b.y);
    r[6] = (short)f2bf(b.z); r[7] = (short)f2bf(b.w);
    return r;
}

__device__ __forceinline__ void gload16(const void* g, void* l) {
    __builtin_amdgcn_global_load_lds(
        (const __attribute__((address_space(1))) unsigned int*)g,
        (__attribute__((address_space(3))) unsigned int*)l, 16, 0, 0);
}

#define VMCNT0() asm volatile("s_waitcnt vmcnt(0)" ::: "memory")

__global__ __launch_bounds__(256)
void zero_f32(float* __restrict__ p, int n) {
    int i = blockIdx.x * 256 + threadIdx.x;
    if (i < n) p[i] = 0.0f;
}

// Wo_eff[n][d] = sum_h Wo[n][h*64+d]   (fp32)
__global__ __launch_bounds__(256)
void wo_eff_kernel(const float* __restrict__ Wo, float* __restrict__ We) {
    int i = blockIdx.x * 256 + threadIdx.x;
    if (i < DM * HDIM) {
        int n = i >> 6, d = i & 63;
        float s = 0.f;
#pragma unroll
        for (int h = 0; h < NH; ++h) s += Wo[(size_t)n * DM + h * HDIM + d];
        We[i] = s;
    }
}

// Y(bf16) = X(f32, 8192xK=1024) @ W(f32, 1024x1024)^T + bias.  128x128 tile, BK=32.
// Staging: reg-load fp32 -> cvt bf16 -> swizzled ds_write_b128.
__global__ __launch_bounds__(256)
void proj_bf16(const float* __restrict__ X, const float* __restrict__ W,
               const float* __restrict__ bias, unsigned short* __restrict__ Y)
{
    __shared__ __align__(16) unsigned short As[128 * 32];
    __shared__ __align__(16) unsigned short Bs[128 * 32];
    const int tid = threadIdx.x;
    const int lane = tid & 63, wid = tid >> 6;
    const int g = lane >> 4, lm = lane & 15;
    const int wr = wid >> 1, wc = wid & 1;
    const int m0 = blockIdx.x * 128, n0 = blockIdx.y * 128;

    int rA[2], cA[2], offA[2];
#pragma unroll
    for (int i = 0; i < 2; ++i) {
        int q = tid + i * 256;
        rA[i] = q >> 2; cA[i] = q & 3;
        offA[i] = rA[i] * 32 + ((cA[i] ^ (rA[i] & 3)) << 3);
    }
    float4 xa[2][2], wa[2][2], xb[2][2], wb[2][2];
#pragma unroll
    for (int i = 0; i < 2; ++i) {
        const float* xp = &X[(size_t)(m0 + rA[i]) * DM + cA[i] * 8];
        const float* wp = &W[(size_t)(n0 + rA[i]) * DM + cA[i] * 8];
        xa[i][0] = *(const float4*)xp; xa[i][1] = *(const float4*)(xp + 4);
        wa[i][0] = *(const float4*)wp; wa[i][1] = *(const float4*)(wp + 4);
    }
    const f32x4 fz = {0.f, 0.f, 0.f, 0.f};
    f32x4 acc[4][4];
#pragma unroll
    for (int i = 0; i < 4; ++i)
#pragma unroll
        for (int j = 0; j < 4; ++j) acc[i][j] = fz;

    for (int t = 0; t < 32; ++t) {
        __syncthreads();
#pragma unroll
        for (int i = 0; i < 2; ++i) {
            *(bf16x8*)&As[offA[i]] = cvt8(xa[i][0], xa[i][1]);
            *(bf16x8*)&Bs[offA[i]] = cvt8(wa[i][0], wa[i][1]);
        }
        if (t < 31) {
            int k0 = (t + 1) * 32;
#pragma unroll
            for (int i = 0; i < 2; ++i) {
                const float* xp = &X[(size_t)(m0 + rA[i]) * DM + k0 + cA[i] * 8];
                const float* wp = &W[(size_t)(n0 + rA[i]) * DM + k0 + cA[i] * 8];
                xb[i][0] = *(const float4*)xp; xb[i][1] = *(const float4*)(xp + 4);
                wb[i][0] = *(const float4*)wp; wb[i][1] = *(const float4*)(wp + 4);
            }
        }
        __syncthreads();
        bf16x8 a[4], b[4];
#pragma unroll
        for (int f = 0; f < 4; ++f) {
            int ra = wr * 64 + f * 16 + lm;
            a[f] = *(const bf16x8*)&As[ra * 32 + (((g) ^ (ra & 3)) << 3)];
            int rb = wc * 64 + f * 16 + lm;
            b[f] = *(const bf16x8*)&Bs[rb * 32 + (((g) ^ (rb & 3)) << 3)];
        }
#pragma unroll
        for (int fm = 0; fm < 4; ++fm)
#pragma unroll
            for (int fn = 0; fn < 4; ++fn)
                acc[fm][fn] = __builtin_amdgcn_mfma_f32_16x16x32_bf16(
                    a[fm], b[fn], acc[fm][fn], 0, 0, 0);
        if (t < 31) {
#pragma unroll
            for (int i = 0; i < 2; ++i) {
                xa[i][0] = xb[i][0]; xa[i][1] = xb[i][1];
                wa[i][0] = wb[i][0]; wa[i][1] = wb[i][1];
            }
        }
    }
    float bn[4];
#pragma unroll
    for (int fn = 0; fn < 4; ++fn) bn[fn] = bias[n0 + wc * 64 + fn * 16 + lm];
#pragma unroll
    for (int fm = 0; fm < 4; ++fm)
#pragma unroll
        for (int i = 0; i < 4; ++i) {
            int m = m0 + wr * 64 + fm * 16 + 4 * g + i;
#pragma unroll
            for (int fn = 0; fn < 4; ++fn) {
                int n = n0 + wc * 64 + fn * 16 + lm;
                Y[(size_t)m * DM + n] = f2bf(acc[fm][fn][i] + bn[fn]);
            }
        }
}

// Vt[((b*NH+h)*64 + d)*SKL + kv] = V[(b*SKL+kv)*DM + h*64 + d]
__global__ __launch_bounds__(256)
void transpose_v(const unsigned short* __restrict__ V, unsigned short* __restrict__ Vt)
{
    __shared__ __align__(16) unsigned short Ts[64][80];
    const int tid = threadIdx.x;
    const int kv0 = blockIdx.x * 64, h = blockIdx.y, b = blockIdx.z;
#pragma unroll
    for (int i = 0; i < 2; ++i) {
        int q = tid + i * 256;
        int r = q >> 3, c = q & 7;
        *(uint4*)&Ts[r][c * 8] =
            *(const uint4*)&V[(size_t)(b * SKL + kv0 + r) * DM + h * HDIM + c * 8];
    }
    __syncthreads();
#pragma unroll
    for (int i = 0; i < 2; ++i) {
        int q = tid + i * 256;
        int d = q >> 3, kc = q & 7;
        union { unsigned short u16[8]; uint4 v; } tw;
#pragma unroll
        for (int e = 0; e < 8; ++e) tw.u16[e] = Ts[kc * 8 + e][d];
        *(uint4*)&Vt[((size_t)(b * NH + h) * HDIM + d) * SKL + kv0 + kc * 8] = tw.v;
    }
}

// Flash: per (b,h,q-tile64). 4 waves, each owns 16 q-rows. bf16 MFMA QK^T + PV,
// fp32 online softmax, fp32 accum; atomically adds head-mean attended.
__global__ __launch_bounds__(256)
void flash_mfma(const unsigned short* __restrict__ Q, const unsigned short* __restrict__ K,
                const unsigned short* __restrict__ Vt, float* __restrict__ mw,
                float* __restrict__ lw, float* __restrict__ am)
{
    __shared__ __align__(16) unsigned short sK[2][64 * 64];
    __shared__ __align__(16) unsigned short sV[2][64 * 64];
    __shared__ __align__(16) unsigned short sP[4][16][72];
    const int tid = threadIdx.x;
    const int lane = tid & 63, wid = tid >> 6;
    const int g = lane >> 4, lm = lane & 15;
    const int q0 = blockIdx.x * 64, h = blockIdx.y, b = blockIdx.z;

    bf16x8 qf[2];
    {
        const unsigned short* qp = &Q[(size_t)(b * SQL + q0 + wid * 16 + lm) * DM + h * HDIM];
        qf[0] = *(const bf16x8*)(qp + g * 8);
        qf[1] = *(const bf16x8*)(qp + 32 + g * 8);
    }
    int rs[2], cs[2];
#pragma unroll
    for (int i = 0; i < 2; ++i) { int q = tid + i * 256; rs[i] = q >> 3; cs[i] = (q & 7) ^ (rs[i] & 7); }

    const unsigned short* Kbase = &K[((size_t)b * SKL) * DM + h * HDIM];
    const unsigned short* Vbase = &Vt[((size_t)(b * NH + h) * HDIM) * SKL];

#pragma unroll
    for (int i = 0; i < 2; ++i) {
        gload16(Kbase + (size_t)rs[i] * DM + cs[i] * 8, &sK[0][(tid + i * 256) * 8]);
        gload16(Vbase + (size_t)rs[i] * SKL + cs[i] * 8, &sV[0][(tid + i * 256) * 8]);
    }
    VMCNT0();
    __syncthreads();

    const f32x4 fz = {0.f, 0.f, 0.f, 0.f};
    float m_run[4], l_run[4];
    f32x4 att[4];
#pragma unroll
    for (int i = 0; i < 4; ++i) { m_run[i] = -INFINITY; l_run[i] = 0.f; att[i] = fz; }

    int cur = 0;
    for (int kt = 0; kt < SKL / 64; ++kt) {
        if (kt + 1 < SKL / 64) {
            int k0 = (kt + 1) * 64;
#pragma unroll
            for (int i = 0; i < 2; ++i) {
                gload16(Kbase + (size_t)(k0 + rs[i]) * DM + cs[i] * 8, &sK[cur ^ 1][(tid + i * 256) * 8]);
                gload16(Vbase + (size_t)rs[i] * SKL + k0 + cs[i] * 8, &sV[cur ^ 1][(tid + i * 256) * 8]);
            }
        }
        // S = Q K^T  (rows q_local = 4g+i, cols kv = nf*16+lm)
        f32x4 s[4];
#pragma unroll
        for (int nf = 0; nf < 4; ++nf) s[nf] = fz;
#pragma unroll
        for (int kk = 0; kk < 2; ++kk)
#pragma unroll
            for (int nf = 0; nf < 4; ++nf) {
                int r = nf * 16 + lm;
                bf16x8 kv = *(const bf16x8*)&sK[cur][r * 64 + (((kk * 4 + g) ^ (r & 7)) << 3)];
                s[nf] = __builtin_amdgcn_mfma_f32_16x16x32_bf16(qf[kk], kv, s[nf], 0, 0, 0);
            }
        float fs[4];
#pragma unroll
        for (int nf = 0; nf < 4; ++nf) s[nf] *= FSCALE;
#pragma unroll
        for (int i = 0; i < 4; ++i) {
            float rm = fmaxf(fmaxf(s[0][i], s[1][i]), fmaxf(s[2][i], s[3][i]));
            rm = fmaxf(rm, __shfl_xor(rm, 1));
            rm = fmaxf(rm, __shfl_xor(rm, 2));
            rm = fmaxf(rm, __shfl_xor(rm, 4));
            rm = fmaxf(rm, __shfl_xor(rm, 8));
            float mnew = fmaxf(m_run[i], rm);
            fs[i] = __expf(m_run[i] - mnew);
            float ps = 0.f;
#pragma unroll
            for (int nf = 0; nf < 4; ++nf) {
                float p = __expf(s[nf][i] - mnew);
                s[nf][i] = p; ps += p;
            }
            ps += __shfl_xor(ps, 1);
            ps += __shfl_xor(ps, 2);
            ps += __shfl_xor(ps, 4);
            ps += __shfl_xor(ps, 8);
            l_run[i] = l_run[i] * fs[i] + ps;
            m_run[i] = mnew;
        }
#pragma unroll
        for (int nf = 0; nf < 4; ++nf)
#pragma unroll
            for (int i = 0; i < 4; ++i) {
                sP[wid][4 * g + i][nf * 16 + lm] = f2bf(s[nf][i]);
                att[nf][i] *= fs[i];
            }
        // att += P @ V
#pragma unroll
        for (int kk = 0; kk < 2; ++kk) {
            bf16x8 ap = *(const bf16x8*)&sP[wid][lm][kk * 32 + g * 8];
#pragma unroll
            for (int nf = 0; nf < 4; ++nf) {
                int r = nf * 16 + lm;
                bf16x8 vv = *(const bf16x8*)&sV[cur][r * 64 + (((kk * 4 + g) ^ (r & 7)) << 3)];
                att[nf] = __builtin_amdgcn_mfma_f32_16x16x32_bf16(ap, vv, att[nf], 0, 0, 0);
            }
        }
        VMCNT0();
        __syncthreads();
        cur ^= 1;
    }
    if (lm == 0) {
#pragma unroll
        for (int i = 0; i < 4; ++i) {
            size_t idx = (size_t)(b * NH + h) * SQL + q0 + wid * 16 + 4 * g + i;
            mw[idx] = m_run[i];
            lw[idx] = l_run[i];
        }
    }
    float inv[4];
#pragma unroll
    for (int i = 0; i < 4; ++i) inv[i] = 1.0f / (l_run[i] * (float)NH);
#pragma unroll
    for (int nf = 0; nf < 4; ++nf)
#pragma unroll
        for (int i = 0; i < 4; ++i)
            atomicAdd(&am[(size_t)(b * SQL + q0 + wid * 16 + 4 * g + i) * HDIM + nf * 16 + lm],
                      att[nf][i] * inv[i]);
}

// Second pass: recompute scores per head via MFMA, emit avg attention tile (fp32).
__global__ __launch_bounds__(256)
void avg_mfma(const unsigned short* __restrict__ Q, const unsigned short* __restrict__ K,
              const float* __restrict__ mw, const float* __restrict__ lw,
              float* __restrict__ avg)
{
    __shared__ __align__(16) unsigned short sQ[2][64 * 64];
    __shared__ __align__(16) unsigned short sK[2][64 * 64];
    __shared__ float mS[NH][64];
    __shared__ float ilS[NH][64];
    const int tid = threadIdx.x;
    const int lane = tid & 63, wid = tid >> 6;
    const int g = lane >> 4, lm = lane & 15;
    const int k0 = blockIdx.x * 64, q0 = blockIdx.y * 64, b = blockIdx.z;

    for (int i = tid; i < NH * 64; i += 256) {
        int hh = i >> 6, qq = i & 63;
        mS[hh][qq] = mw[(size_t)(b * NH + hh) * SQL + q0 + qq];
        ilS[hh][qq] = 1.0f / (lw[(size_t)(b * NH + hh) * SQL + q0 + qq] * (float)NH);
    }
    int rs[2], cs[2];
#pragma unroll
    for (int i = 0; i < 2; ++i) { int q = tid + i * 256; rs[i] = q >> 3; cs[i] = (q & 7) ^ (rs[i] & 7); }

    const unsigned short* Qbase = &Q[(size_t)(b * SQL + q0) * DM];
    const unsigned short* Kbase = &K[(size_t)(b * SKL + k0) * DM];
#pragma unroll
    for (int i = 0; i < 2; ++i) {
        gload16(Qbase + (size_t)rs[i] * DM + cs[i] * 8, &sQ[0][(tid + i * 256) * 8]);
        gload16(Kbase + (size_t)rs[i] * DM + cs[i] * 8, &sK[0][(tid + i * 256) * 8]);
    }
    VMCNT0();
    __syncthreads();

    const f32x4 fz = {0.f, 0.f, 0.f, 0.f};
    f32x4 acc[4];
#pragma unroll
    for (int nf = 0; nf < 4; ++nf) acc[nf] = fz;
    int cur = 0;
    for (int hh = 0; hh < NH; ++hh) {
        if (hh + 1 < NH) {
#pragma unroll
            for (int i = 0; i < 2; ++i) {
                gload16(Qbase + (size_t)rs[i] * DM + (hh + 1) * HDIM + cs[i] * 8,
                        &sQ[cur ^ 1][(tid + i * 256) * 8]);
                gload16(Kbase + (size_t)rs[i] * DM + (hh + 1) * HDIM + cs[i] * 8,
                        &sK[cur ^ 1][(tid + i * 256) * 8]);
            }
        }
        f32x4 s[4];
#pragma unroll
        for (int nf = 0; nf < 4; ++nf) s[nf] = fz;
#pragma unroll
        for (int kk = 0; kk < 2; ++kk) {
            int ra = wid * 16 + lm;
            bf16x8 a = *(const bf16x8*)&sQ[cur][ra * 64 + (((kk * 4 + g) ^ (ra & 7)) << 3)];
#pragma unroll
            for (int nf = 0; nf < 4; ++nf) {
                int r = nf * 16 + lm;
                bf16x8 kv = *(const bf16x8*)&sK[cur][r * 64 + (((kk * 4 + g) ^ (r & 7)) << 3)];
                s[nf] = __builtin_amdgcn_mfma_f32_16x16x32_bf16(a, kv, s[nf], 0, 0, 0);
            }
        }
#pragma unroll
        for (int i = 0; i < 4; ++i) {
            int ql = wid * 16 + 4 * g + i;
            float mv = mS[hh][ql], il = ilS[hh][ql];
#pragma unroll
            for (int nf = 0; nf < 4; ++nf)
                acc[nf][i] += __expf(fmaf(s[nf][i], FSCALE, -mv)) * il;
        }
        VMCNT0();
        __syncthreads();
        cur ^= 1;
    }
#pragma unroll
    for (int nf = 0; nf < 4; ++nf)
#pragma unroll
        for (int i = 0; i < 4; ++i)
            avg[(size_t)(b * SQL + q0 + wid * 16 + 4 * g + i) * SKL + k0 + nf * 16 + lm] =
                acc[nf][i];
}

// out = attended_mean @ Wo_eff^T + bo  (M=8192, N=1024, K=64, fp32)
__global__ __launch_bounds__(256)
void out_gemm(const float* __restrict__ amp, const float* __restrict__ We,
              const float* __restrict__ bo, float* __restrict__ out)
{
    __shared__ float As[64][68];
    __shared__ float Bs[64][68];
    const int m0 = blockIdx.x << 6, n0 = blockIdx.y << 6;
    const int tid = threadIdx.x;
    const int tx = tid & 15, ty = tid >> 4;
    const int lrow = tid >> 4, ldc = (tid & 15) << 2;
#pragma unroll
    for (int rr = 0; rr < 4; ++rr) {
        int r = (rr << 4) + lrow;
        float4 a = *reinterpret_cast<const float4*>(&amp[(size_t)(m0 + r) * HDIM + ldc]);
        float4 w = *reinterpret_cast<const float4*>(&We[(size_t)(n0 + r) * HDIM + ldc]);
        As[ldc + 0][r] = a.x; As[ldc + 1][r] = a.y; As[ldc + 2][r] = a.z; As[ldc + 3][r] = a.w;
        Bs[ldc + 0][r] = w.x; Bs[ldc + 1][r] = w.y; Bs[ldc + 2][r] = w.z; Bs[ldc + 3][r] = w.w;
    }
    __syncthreads();
    float acc[4][4] = {};
    for (int d = 0; d < 64; ++d) {
        float4 av = *reinterpret_cast<const float4*>(&As[d][ty << 2]);
        float4 bv = *reinterpret_cast<const float4*>(&Bs[d][tx << 2]);
        float aa[4] = {av.x, av.y, av.z, av.w};
        float bb[4] = {bv.x, bv.y, bv.z, bv.w};
#pragma unroll
        for (int i = 0; i < 4; ++i)
#pragma unroll
            for (int j = 0; j < 4; ++j)
                acc[i][j] = fmaf(aa[i], bb[j], acc[i][j]);
    }
    float4 bv = *reinterpret_cast<const float4*>(&bo[n0 + (tx << 2)]);
    float bb4[4] = {bv.x, bv.y, bv.z, bv.w};
#pragma unroll
    for (int i = 0; i < 4; ++i) {
        int m = m0 + (ty << 2) + i;
        float4 o = make_float4(acc[i][0] + bb4[0], acc[i][1] + bb4[1],
                               acc[i][2] + bb4[2], acc[i][3] + bb4[3]);
        *reinterpret_cast<float4*>(&out[(size_t)m * DM + n0 + (tx << 2)]) = o;
    }
}

extern "C" void kernel_launch(void* const* d_in, const int* in_sizes, int n_in,
                              void* d_out, int out_size, void* d_ws, size_t ws_size,
                              hipStream_t stream)
{
    const float* query = (const float*)d_in[0];
    const float* key   = (const float*)d_in[1];
    const float* value = (const float*)d_in[2];
    const float* Wq = (const float*)d_in[3];
    const float* bq = (const float*)d_in[4];
    const float* Wk = (const float*)d_in[5];
    const float* bk = (const float*)d_in[6];
    const float* Wv = (const float*)d_in[7];
    const float* bv = (const float*)d_in[8];
    const float* Wo = (const float*)d_in[9];
    const float* bo = (const float*)d_in[10];

    float* out0 = (float*)d_out;                      // (B,SQ,D)
    float* out_avg = out0 + (size_t)BB * SQL * DM;    // (B,SQ,SK)

    const size_t nQ = (size_t)BB * SQL * DM;          // 8388608
    const size_t nML = (size_t)BB * NH * SQL;         // 131072
    const size_t nAM = (size_t)BB * SQL * HDIM;       // 524288
    unsigned short* Qb = (unsigned short*)d_ws;
    unsigned short* Kb = Qb + nQ;
    unsigned short* Vb = Kb + nQ;
    unsigned short* Vt = Vb + nQ;
    float* mw  = (float*)(Vt + nQ);
    float* lw  = mw + nML;
    float* amb = lw + nML;
    float* We  = amb + nAM;

    dim3 blk(256);
    zero_f32<<<dim3((unsigned)((nAM + 255) / 256)), blk, 0, stream>>>(amb, (int)nAM);
    wo_eff_kernel<<<dim3((DM * HDIM + 255) / 256), blk, 0, stream>>>(Wo, We);

    dim3 gp(64, 8);
    proj_bf16<<<gp, blk, 0, stream>>>(query, Wq, bq, Qb);
    proj_bf16<<<gp, blk, 0, stream>>>(key,   Wk, bk, Kb);
    proj_bf16<<<gp, blk, 0, stream>>>(value, Wv, bv, Vb);

    transpose_v<<<dim3(32, 16, 4), blk, 0, stream>>>(Vb, Vt);
    flash_mfma<<<dim3(32, 16, 4), blk, 0, stream>>>(Qb, Kb, Vt, mw, lw, amb);
    avg_mfma<<<dim3(32, 32, 4), blk, 0, stream>>>(Qb, Kb, mw, lw, out_avg);
    out_gemm<<<dim3(128, 16), blk, 0, stream>>>(amb, We, bo, out0);
}